// Round 4
// baseline (9247.131 us; speedup 1.0000x reference)
//
#include <hip/hip_runtime.h>

typedef unsigned short ushort;
typedef unsigned int uint32;
typedef __attribute__((ext_vector_type(8))) short bf16x8;
typedef __attribute__((ext_vector_type(4))) float f32x4;

#define DEV __device__ __forceinline__

DEV ushort bf16_rn(float f){
  uint32 u = __float_as_uint(f);
  u += 0x7fff + ((u >> 16) & 1);
  return (ushort)(u >> 16);
}
DEV float bf16_to_f(ushort h){ return __uint_as_float(((uint32)h) << 16); }

DEV float gelu_f(float x){
  float x3 = x*x*x;
  float tt = 0.7978845608028654f * (x + 0.044715f * x3);
  float e = __expf(2.f * tt);
  float th = 1.f - 2.f / (e + 1.f);   // tanh(tt), overflow-safe
  return 0.5f * x * (1.f + th);
}

typedef __attribute__((address_space(1))) const void GV;
typedef __attribute__((address_space(3))) void LV;
#define ASYNC16(g, l) __builtin_amdgcn_global_load_lds((GV*)(g), (LV*)(l), 16, 0, 0)

// ---------------------------------------------------------------------------
// Fallback: zero d_out (used only if ws_size is insufficient, so the bench
// reports a clean validation failure instead of a wild-write container death)
// ---------------------------------------------------------------------------
__global__ void zero_kernel(float* __restrict__ out, int n4)
{
  int i = blockIdx.x * 256 + threadIdx.x;
  int stride = gridDim.x * 256;
  for (; i < n4; i += stride)
    *(float4*)(out + (size_t)i * 4) = make_float4(0.f, 0.f, 0.f, 0.f);
}

// ---------------------------------------------------------------------------
// LayerNorm: x[4096 rows][4096] -> xn3 bf16 [4096][3*4096], A-pattern (hi,hi,lo)
// ---------------------------------------------------------------------------
__global__ __launch_bounds__(256) void ln_kernel(
    const float* __restrict__ x, const float* __restrict__ gam,
    const float* __restrict__ bet, ushort* __restrict__ xn3)
{
  int row = blockIdx.x, t = threadIdx.x;
  const float* xr = x + (size_t)row * 4096;
  float4 v[4];
  float s = 0.f, s2 = 0.f;
#pragma unroll
  for (int i = 0; i < 4; i++){
    v[i] = *(const float4*)(xr + i*1024 + t*4);
    s  += v[i].x + v[i].y + v[i].z + v[i].w;
    s2 += v[i].x*v[i].x + v[i].y*v[i].y + v[i].z*v[i].z + v[i].w*v[i].w;
  }
#pragma unroll
  for (int m = 1; m < 64; m <<= 1){ s += __shfl_xor(s, m, 64); s2 += __shfl_xor(s2, m, 64); }
  __shared__ float red[8];
  int wv = t >> 6;
  if ((t & 63) == 0){ red[wv] = s; red[4 + wv] = s2; }
  __syncthreads();
  s  = red[0] + red[1] + red[2] + red[3];
  s2 = red[4] + red[5] + red[6] + red[7];
  float mu  = s * (1.f/4096.f);
  float var = s2 * (1.f/4096.f) - mu*mu;
  float rstd = rsqrtf(var + 1e-5f);
#pragma unroll
  for (int i = 0; i < 4; i++){
    int k0 = i*1024 + t*4;
    float4 g4 = *(const float4*)(gam + k0);
    float4 b4 = *(const float4*)(bet + k0);
    float xv[4] = {v[i].x, v[i].y, v[i].z, v[i].w};
    float gv[4] = {g4.x, g4.y, g4.z, g4.w};
    float bv[4] = {b4.x, b4.y, b4.z, b4.w};
    ushort h[4], lo[4];
#pragma unroll
    for (int j = 0; j < 4; j++){
      float xn = (xv[j] - mu) * rstd * gv[j] + bv[j];
      h[j]  = bf16_rn(xn);
      lo[j] = bf16_rn(xn - bf16_to_f(h[j]));
    }
    // A-pattern per k: hi,hi,lo
    uint32 u0 = (uint32)h[0]  | ((uint32)h[0]  << 16);
    uint32 u1 = (uint32)lo[0] | ((uint32)h[1]  << 16);
    uint32 u2 = (uint32)h[1]  | ((uint32)lo[1] << 16);
    uint32 u3 = (uint32)h[2]  | ((uint32)h[2]  << 16);
    uint32 u4 = (uint32)lo[2] | ((uint32)h[3]  << 16);
    uint32 u5 = (uint32)h[3]  | ((uint32)lo[3] << 16);
    uint2* dst = (uint2*)(xn3 + (size_t)row * 12288 + 3*k0);
    dst[0] = make_uint2(u0, u1); dst[1] = make_uint2(u2, u3); dst[2] = make_uint2(u4, u5);
  }
}

// ---------------------------------------------------------------------------
// Weight transpose+split: W[K][N] f32 -> W3[N][3K] bf16, B-pattern (hi,lo,hi)
// ---------------------------------------------------------------------------
__global__ __launch_bounds__(256) void wtrans_kernel(
    const float* __restrict__ W, ushort* __restrict__ W3, int K, int N)
{
  __shared__ float tile[32][33];
  int n0 = blockIdx.x * 32, k0 = blockIdx.y * 32;
  int t = threadIdx.x;
  int c = t & 31, r0 = t >> 5;
#pragma unroll
  for (int j = 0; j < 4; j++){
    int r = r0 + j*8;
    tile[r][c] = W[(size_t)(k0 + r) * N + n0 + c];
  }
  __syncthreads();
  int nl = t >> 3, kq = (t & 7) * 4;
  ushort h[4], lo[4];
#pragma unroll
  for (int i = 0; i < 4; i++){
    float f = tile[kq + i][nl];
    h[i]  = bf16_rn(f);
    lo[i] = bf16_rn(f - bf16_to_f(h[i]));
  }
  // B-pattern per k: hi,lo,hi
  uint32 u0 = (uint32)h[0]  | ((uint32)lo[0] << 16);
  uint32 u1 = (uint32)h[0]  | ((uint32)h[1]  << 16);
  uint32 u2 = (uint32)lo[1] | ((uint32)h[1]  << 16);
  uint32 u3 = (uint32)h[2]  | ((uint32)lo[2] << 16);
  uint32 u4 = (uint32)h[2]  | ((uint32)h[3]  << 16);
  uint32 u5 = (uint32)lo[3] | ((uint32)h[3]  << 16);
  uint2* dst = (uint2*)(W3 + (size_t)(n0 + nl) * 3 * K + (size_t)3 * (k0 + kq));
  dst[0] = make_uint2(u0, u1); dst[1] = make_uint2(u2, u3); dst[2] = make_uint2(u4, u5);
}

// ---------------------------------------------------------------------------
// GEMM C[4096][N] = A[4096][K] * B[N][K]^T   (bf16 in), m97 structure.
// EPI: 0 plain f32 out, 1 f32 +bias, 2 gelu(x+bias) -> bf16 split (hi,hi,lo)
//      3 f32 add-into-C
// ---------------------------------------------------------------------------
template<int EPI>
__global__ __launch_bounds__(256) void gemm_bt(
    const ushort* __restrict__ A, const ushort* __restrict__ Bm,
    void* __restrict__ Cv, const float* __restrict__ bias, int N, int K)
{
  __shared__ ushort As[128 * 64];
  __shared__ ushort Bs[128 * 64];
  int nbn = N >> 7;
  int nwg = (4096 >> 7) * nbn;
  int per = nwg >> 3;                    // grids are multiples of 8
  int wg  = blockIdx.x;
  int swz = (wg & 7) * per + (wg >> 3);  // XCD-aware swizzle
  int bm = swz / nbn, bn = swz - bm * nbn;
  int t = threadIdx.x;
  int w = t >> 6, l = t & 63;
  int l15 = l & 15, l16 = l >> 4;
  int wr = w >> 1, wc = w & 1;
  const ushort* Ab = A  + (size_t)bm * 128 * K;
  const ushort* Bb = Bm + (size_t)bn * 128 * K;
  f32x4 acc[4][4] = {};
  for (int k0 = 0; k0 < K; k0 += 64){
    __syncthreads();
#pragma unroll
    for (int i = 0; i < 4; i++){
      int c = i*256 + t;
      ASYNC16(Ab + (size_t)(c >> 3) * K + k0 + (c & 7) * 8, As + c*8);
      ASYNC16(Bb + (size_t)(c >> 3) * K + k0 + (c & 7) * 8, Bs + c*8);
    }
    __syncthreads();
#pragma unroll
    for (int kk = 0; kk < 64; kk += 32){
      bf16x8 af[4], bfr[4];
#pragma unroll
      for (int mi = 0; mi < 4; mi++)
        af[mi] = *(const bf16x8*)(As + (wr*64 + mi*16 + l15)*64 + kk + l16*8);
#pragma unroll
      for (int ni = 0; ni < 4; ni++)
        bfr[ni] = *(const bf16x8*)(Bs + (wc*64 + ni*16 + l15)*64 + kk + l16*8);
#pragma unroll
      for (int mi = 0; mi < 4; mi++)
#pragma unroll
        for (int ni = 0; ni < 4; ni++)
          acc[mi][ni] = __builtin_amdgcn_mfma_f32_16x16x32_bf16(af[mi], bfr[ni], acc[mi][ni], 0, 0, 0);
    }
  }
  float* C = (float*)Cv;
  ushort* H = (ushort*)Cv;
#pragma unroll
  for (int mi = 0; mi < 4; mi++){
    int row = bm*128 + wr*64 + mi*16 + l16*4;
#pragma unroll
    for (int ni = 0; ni < 4; ni++){
      int col = bn*128 + wc*64 + ni*16 + l15;
#pragma unroll
      for (int r = 0; r < 4; r++){
        float v = acc[mi][ni][r];
        if constexpr (EPI == 2){
          v = gelu_f(v + bias[col]);
          ushort hh = bf16_rn(v);
          ushort ll = bf16_rn(v - bf16_to_f(hh));
          size_t bb = (size_t)(row + r) * 3 * N + 3 * (size_t)col;
          H[bb] = hh; H[bb + 1] = hh; H[bb + 2] = ll;   // A-pattern hi,hi,lo
        } else {
          size_t idx = (size_t)(row + r) * N + col;
          if constexpr (EPI == 1) v += bias[col];
          if constexpr (EPI == 3) v += C[idx];
          C[idx] = v;
        }
      }
    }
  }
}

// ---------------------------------------------------------------------------
// RoPE + cast: qkv f32 [token][16*768] -> qb,kb bf16 [bh][s][256]; q *= 1/16
// ---------------------------------------------------------------------------
__global__ void rope_kernel(const float* __restrict__ qkv,
                            ushort* __restrict__ qb, ushort* __restrict__ kb)
{
  int token = blockIdx.x, h = blockIdx.y, t = threadIdx.x; // 64 threads
  int s = token & 2047, b = token >> 11;
  int d0 = t * 4;
  const float* base = qkv + (size_t)token * 12288 + (size_t)h * 768;
  float4 q = *(const float4*)(base + d0);
  float4 k = *(const float4*)(base + 512 + d0);
  if (d0 < 64){
    float qv[4] = {q.x, q.y, q.z, q.w};
    float kv[4] = {k.x, k.y, k.z, k.w};
#pragma unroll
    for (int j = 0; j < 2; j++){
      int i = (d0 >> 1) + j;                       // pair index 0..31
      double freq = exp2(-(double)i * 0.4152410118609203); // 10000^{-i/32}
      double ang  = fmod((double)s * freq, 6.283185307179586476925287);
      float af = (float)ang, sn, cs;
      sincosf(af, &sn, &cs);
      float e = qv[2*j], o = qv[2*j+1];
      qv[2*j]   = e*cs - o*sn;
      qv[2*j+1] = o*cs + e*sn;
      e = kv[2*j]; o = kv[2*j+1];
      kv[2*j]   = e*cs - o*sn;
      kv[2*j+1] = o*cs + e*sn;
    }
    q = make_float4(qv[0], qv[1], qv[2], qv[3]);
    k = make_float4(kv[0], kv[1], kv[2], kv[3]);
  }
  size_t idx = ((size_t)(b*16 + h) * 2048 + s) * 256 + d0;
  ushort4 qo, ko;
  qo.x = bf16_rn(q.x * 0.0625f); qo.y = bf16_rn(q.y * 0.0625f);
  qo.z = bf16_rn(q.z * 0.0625f); qo.w = bf16_rn(q.w * 0.0625f);
  ko.x = bf16_rn(k.x); ko.y = bf16_rn(k.y); ko.z = bf16_rn(k.z); ko.w = bf16_rn(k.w);
  *(ushort4*)(qb + idx) = qo;
  *(ushort4*)(kb + idx) = ko;
}

// ---------------------------------------------------------------------------
// V transpose: qkv f32 v-cols -> vt bf16 [bh][d(256)][s(2048)]
// ---------------------------------------------------------------------------
__global__ __launch_bounds__(256) void vtrans_kernel(
    const float* __restrict__ qkv, ushort* __restrict__ vt)
{
  __shared__ float tile[32][33];
  int s0 = blockIdx.x * 32, d0 = blockIdx.y * 32, bh = blockIdx.z;
  int b = bh >> 4, h = bh & 15;
  int t = threadIdx.x;
  int c = t & 31, r0 = t >> 5;
#pragma unroll
  for (int j = 0; j < 4; j++){
    int sl = r0 + j*8;
    tile[sl][c] = qkv[((size_t)(b*2048 + s0 + sl)) * 12288 + h*768 + 256 + d0 + c];
  }
  __syncthreads();
  int dl = t >> 3, s4 = (t & 7) * 4;
  ushort4 o;
  o.x = bf16_rn(tile[s4+0][dl]); o.y = bf16_rn(tile[s4+1][dl]);
  o.z = bf16_rn(tile[s4+2][dl]); o.w = bf16_rn(tile[s4+3][dl]);
  *(ushort4*)(vt + ((size_t)bh*256 + d0 + dl) * 2048 + s0 + s4) = o;
}

// ---------------------------------------------------------------------------
// Flash attention, causal. Block: (qb,h,b), 256 thr (4 waves x 16 q-rows).
// q pre-scaled by 1/16. KV tile 32. Output: av3 bf16 split (hi,hi,lo).
// ---------------------------------------------------------------------------
__global__ __launch_bounds__(256) void attn_kernel(
    const ushort* __restrict__ qg, const ushort* __restrict__ kg,
    const ushort* __restrict__ vg, const float* __restrict__ bias,
    ushort* __restrict__ av3)
{
  constexpr int KR = 264;  // K row stride (ushorts): 512B + 16B pad
  constexpr int VR = 40;   // V/P row stride (ushorts): 64B + 16B pad
  __shared__ ushort Ks[32 * KR];
  __shared__ ushort Vs[256 * VR];
  __shared__ ushort Ps[4][16 * VR];
  int qb = blockIdx.x, h = blockIdx.y, b = blockIdx.z;
  int bh = b*16 + h;
  int t = threadIdx.x, w = t >> 6, l = t & 63;
  int l15 = l & 15, l16 = l >> 4;
  const ushort* qbase = qg + (size_t)bh * 2048 * 256;
  const ushort* kbase = kg + (size_t)bh * 2048 * 256;
  const ushort* vbase = vg + (size_t)bh * 256 * 2048;
  int qrow = qb*64 + w*16 + l15;
  bf16x8 qf[8];
#pragma unroll
  for (int c = 0; c < 8; c++)
    qf[c] = *(const bf16x8*)(qbase + (size_t)qrow * 256 + c*32 + l16*8);
  f32x4 o[16] = {};
  float mrow[4] = {-3e38f, -3e38f, -3e38f, -3e38f};
  float lrow[4] = {0.f, 0.f, 0.f, 0.f};
  int nkv = 2*qb + 2;
  for (int kvb = 0; kvb < nkv; ++kvb){
    int kv0 = kvb * 32;
    __syncthreads();
    // stage K tile [32][256] -> Ks (padded rows)
#pragma unroll
    for (int i = 0; i < 4; i++){
      int c = i*256 + t; int row = c >> 5, off = c & 31;
      int4 d = *(const int4*)(kbase + (size_t)(kv0 + row) * 256 + off*8);
      *(int4*)(Ks + row*KR + off*8) = d;
    }
    // stage V^T tile [256][32] -> Vs (padded rows)
#pragma unroll
    for (int i = 0; i < 4; i++){
      int c = i*256 + t; int row = c >> 2, off = c & 3;
      int4 d = *(const int4*)(vbase + (size_t)row * 2048 + kv0 + off*8);
      *(int4*)(Vs + row*VR + off*8) = d;
    }
    __syncthreads();
    // S = Q K^T  (2 kv sub-tiles of 16)
    f32x4 sa[2] = {};
#pragma unroll
    for (int kt = 0; kt < 2; kt++){
#pragma unroll
      for (int c = 0; c < 8; c++){
        bf16x8 kf = *(const bf16x8*)(Ks + (kt*16 + l15)*KR + c*32 + l16*8);
        sa[kt] = __builtin_amdgcn_mfma_f32_16x16x32_bf16(qf[c], kf, sa[kt], 0, 0, 0);
      }
    }
    // mask + bias + online softmax
    float p0a[4], p1a[4], mt[4];
#pragma unroll
    for (int r = 0; r < 4; r++){
      int qr = qb*64 + w*16 + l16*4 + r;
      int c0 = kv0 + l15, c1 = kv0 + 16 + l15;
      float s0v = (c0 <= qr) ? sa[0][r] + bias[(size_t)qr*2048 + c0] : -1e30f;
      float s1v = (c1 <= qr) ? sa[1][r] + bias[(size_t)qr*2048 + c1] : -1e30f;
      p0a[r] = s0v; p1a[r] = s1v;
      float m = fmaxf(s0v, s1v);
      m = fmaxf(m, __shfl_xor(m, 1, 64));
      m = fmaxf(m, __shfl_xor(m, 2, 64));
      m = fmaxf(m, __shfl_xor(m, 4, 64));
      m = fmaxf(m, __shfl_xor(m, 8, 64));
      mt[r] = m;
    }
#pragma unroll
    for (int r = 0; r < 4; r++){
      float mn = fmaxf(mrow[r], mt[r]);
      float alpha = __expf(mrow[r] - mn);
      mrow[r] = mn;
      float p0 = __expf(p0a[r] - mn);
      float p1 = __expf(p1a[r] - mn);
      float rs = p0 + p1;
      rs += __shfl_xor(rs, 1, 64);
      rs += __shfl_xor(rs, 2, 64);
      rs += __shfl_xor(rs, 4, 64);
      rs += __shfl_xor(rs, 8, 64);
      lrow[r] = lrow[r] * alpha + rs;
#pragma unroll
      for (int dt = 0; dt < 16; dt++) o[dt][r] *= alpha;
      ushort* pw = Ps[w] + (l16*4 + r) * VR;
      pw[l15]      = bf16_rn(p0);
      pw[16 + l15] = bf16_rn(p1);
    }
    asm volatile("s_waitcnt lgkmcnt(0)" ::: "memory");
    __builtin_amdgcn_sched_barrier(0);
    // O += P V
    bf16x8 pa = *(const bf16x8*)(Ps[w] + l15*VR + l16*8);
#pragma unroll
    for (int dt = 0; dt < 16; dt++){
      bf16x8 vf = *(const bf16x8*)(Vs + (dt*16 + l15)*VR + l16*8);
      o[dt] = __builtin_amdgcn_mfma_f32_16x16x32_bf16(pa, vf, o[dt], 0, 0, 0);
    }
  }
  // epilogue: write bf16 split (hi,hi,lo) into av3 [4096][3*4096]
#pragma unroll
  for (int r = 0; r < 4; r++){
    float inv = 1.f / lrow[r];
    int tok = b*2048 + qb*64 + w*16 + l16*4 + r;
    ushort* dst = av3 + (size_t)tok * 12288;
#pragma unroll
    for (int dt = 0; dt < 16; dt++){
      float v = o[dt][r] * inv;
      ushort hh = bf16_rn(v);
      ushort ll = bf16_rn(v - bf16_to_f(hh));
      size_t bb = 3 * (size_t)(h*256 + dt*16 + l15);
      dst[bb] = hh; dst[bb + 1] = hh; dst[bb + 2] = ll;
    }
  }
}

// ---------------------------------------------------------------------------
extern "C" void kernel_launch(void* const* d_in, const int* in_sizes, int n_in,
                              void* d_out, int out_size, void* d_ws, size_t ws_size,
                              hipStream_t stream)
{
  (void)in_sizes; (void)n_in;
  const float* x         = (const float*)d_in[0];
  const float* attn_bias = (const float*)d_in[1];
  const float* ln_scale  = (const float*)d_in[2];
  const float* ln_offset = (const float*)d_in[3];
  const float* w_qkv     = (const float*)d_in[4];
  const float* w_o       = (const float*)d_in[5];
  const float* w_in      = (const float*)d_in[6];
  const float* b_in      = (const float*)d_in[7];
  const float* w_out     = (const float*)d_in[8];
  const float* b_out     = (const float*)d_in[9];
  float* out = (float*)d_out;

  // Workspace arena, 960 MiB, liveness-exact slotting:
  //   slot1 [  0M,384M): wqkv3 (ph1) -> win3 (ph3) -> wout3 (ph4)
  //   slot2 [384M,768M): qkvf+qbuf+kbuf+vtb (ph1-2) -> h3 (ph3-4)
  //   slot3 [768M,864M): xn3 (ph1-3) -> wo3 (ph5)
  //   slot4 [864M,960M): av3 (ph2-5)
  const size_t MB = 1024*1024;
  const size_t REQUIRED = 960*MB;
  if (ws_size < REQUIRED){
    // insufficient scratch: fail validation cleanly, never write OOB
    zero_kernel<<<2048, 256, 0, stream>>>(out, out_size/4);
    return;
  }
  char* ws = (char*)d_ws;
  char* slot1 = ws;
  char* slot2 = ws + 384*MB;
  char* slot3 = ws + 768*MB;
  char* slot4 = ws + 864*MB;

  ushort* wqkv3 = (ushort*)slot1;                // [12288][12288] bf16  288M
  ushort* win3  = (ushort*)slot1;                // [16384][12288] bf16  384M
  ushort* wout3 = (ushort*)slot1;                // [4096][49152]  bf16  384M
  float*  qkvf  = (float*)slot2;                 // [4096][12288]  f32   192M
  ushort* qbuf  = (ushort*)(slot2 + 192*MB);     // [32][2048][256] bf16  32M
  ushort* kbuf  = (ushort*)(slot2 + 224*MB);     //                       32M
  ushort* vtb   = (ushort*)(slot2 + 256*MB);     // [32][256][2048] bf16  32M
  ushort* h3    = (ushort*)slot2;                // [4096][49152]  bf16  384M
  ushort* xn3   = (ushort*)slot3;                // [4096][12288]  bf16   96M
  ushort* wo3   = (ushort*)slot3;                // [4096][12288]  bf16   96M
  ushort* av3   = (ushort*)slot4;                // [4096][12288]  bf16   96M

  // Phase 1: LN, QKV projection
  ln_kernel<<<4096, 256, 0, stream>>>(x, ln_scale, ln_offset, xn3);
  wtrans_kernel<<<dim3(12288/32, 4096/32), 256, 0, stream>>>(w_qkv, wqkv3, 4096, 12288);
  gemm_bt<0><<<32*96, 256, 0, stream>>>(xn3, wqkv3, qkvf, nullptr, 12288, 12288);

  // Phase 2: attention (writes av3 split-bf16 directly)
  rope_kernel<<<dim3(4096, 16), 64, 0, stream>>>(qkvf, qbuf, kbuf);
  vtrans_kernel<<<dim3(64, 8, 32), 256, 0, stream>>>(qkvf, vtb);
  attn_kernel<<<dim3(32, 16, 2), 256, 0, stream>>>(qbuf, kbuf, vtb, attn_bias, av3);

  // Phase 3: MLP-in (fused gelu + split-cast -> h3); wqkv3 dead -> win3 in slot1;
  //          attn done -> h3 overwrites slot2
  wtrans_kernel<<<dim3(16384/32, 4096/32), 256, 0, stream>>>(w_in, win3, 4096, 16384);
  gemm_bt<2><<<32*128, 256, 0, stream>>>(xn3, win3, h3, b_in, 16384, 12288);

  // Phase 4: MLP-out; win3 dead -> wout3 in slot1
  wtrans_kernel<<<dim3(4096/32, 16384/32), 256, 0, stream>>>(w_out, wout3, 16384, 4096);
  gemm_bt<1><<<32*32, 256, 0, stream>>>(h3, wout3, out, b_out, 4096, 49152);

  // Phase 5: attention output projection (add into out); xn3 dead -> wo3 in slot3
  wtrans_kernel<<<dim3(4096/32, 4096/32), 256, 0, stream>>>(w_o, wo3, 4096, 4096);
  gemm_bt<3><<<32*32, 256, 0, stream>>>(av3, wo3, out, nullptr, 4096, 12288);
}